// Round 4
// baseline (273.277 us; speedup 1.0000x reference)
//
#include <hip/hip_runtime.h>

#define BB 32
#define IDF 64
#define QL 16384
#define CDF 768
#define SL 18
#define SLP 20             // padded row stride for ctx_l / sT
#define ADIM 100

__device__ __forceinline__ void fma4(float4& a, const float4 v, const float s) {
    a.x += v.x * s; a.y += v.y * s; a.z += v.z * s; a.w += v.w * s;
}

// ---------------- Kernel 1: sT[b,i,s] = sum_c wic[i,c] * ctx[b,c,s]
// grid = (32, 4), block = 256 (4 waves). Block (b,g): rows i in [16g, 16g+16).
// Loop order: k outer, ii inner -> ctx row regs loaded once per k (4x fewer
// LDS reads than row-outer; the stride-20 b128 read is 8-way-conflicted).
__global__ __launch_bounds__(256, 2) void k1_source(
        const float* __restrict__ ctx,      // [B, CDF, SL]
        const float* __restrict__ wic,      // [IDF, CDF]
        float* __restrict__ sT)             // ws: [B, IDF, SLP]
{
    __shared__ __align__(16) float ctx_l[CDF * SLP];   // 61440 B
    const int b = blockIdx.x;
    const int g = blockIdx.y;
    const float* ctxb = ctx + (size_t)b * CDF * SL;

    for (int t = threadIdx.x; t < CDF * SL; t += 256) {
        const int c = t / SL;
        const int s = t - c * SL;
        ctx_l[c * SLP + s] = ctxb[t];
    }
    __syncthreads();

    const int wave = threadIdx.x >> 6;
    const int lane = threadIdx.x & 63;
    const int i0 = g * 16 + wave * 4;

    float acc[4][SL];
#pragma unroll
    for (int ii = 0; ii < 4; ii++)
#pragma unroll
        for (int s = 0; s < SL; s++) acc[ii][s] = 0.f;

    for (int k = 0; k < CDF / 64; k++) {
        const int c = k * 64 + lane;
        float wv[4];
#pragma unroll
        for (int ii = 0; ii < 4; ii++) wv[ii] = wic[(i0 + ii) * CDF + c];  // coalesced
        float r[SLP];
        const float4* r4 = (const float4*)&ctx_l[c * SLP];
        ((float4*)r)[0] = r4[0];
        ((float4*)r)[1] = r4[1];
        ((float4*)r)[2] = r4[2];
        ((float4*)r)[3] = r4[3];
        ((float4*)r)[4] = r4[4];
#pragma unroll
        for (int ii = 0; ii < 4; ii++)
#pragma unroll
            for (int s = 0; s < SL; s++) acc[ii][s] += wv[ii] * r[s];
    }

#pragma unroll
    for (int ii = 0; ii < 4; ii++) {
#pragma unroll
        for (int s = 0; s < SL; s++) {
            float a = acc[ii][s];
#pragma unroll
            for (int off = 32; off; off >>= 1) a += __shfl_xor(a, off, 64);
            if (lane == 0) sT[((size_t)b * IDF + i0 + ii) * SLP + s] = a;
        }
    }
}

// ---------------- Kernel 2: scores -> softmax -> dot with v.  HBM-bound main pass.
// grid = (16, 32), block = 256. Each thread: 4 consecutive q (float4 stream).
__global__ __launch_bounds__(256, 2) void k2_attn(
        const float* __restrict__ inp,     // [B, IDF, QL]
        const float* __restrict__ sT,      // [B, IDF, SLP]
        const float* __restrict__ conv_w,  // [IDF]
        const float* __restrict__ conv_b,  // [1]
        float* __restrict__ wq)            // ws: [B, QL]
{
    __shared__ __align__(16) float st_l[IDF * SLP];   // 5120 B
    __shared__ float cw_l[IDF];
    __shared__ float v_l[SL];
    const int b = blockIdx.y;
    const int tid = threadIdx.x;

    for (int t = tid; t < IDF * SLP; t += 256) st_l[t] = sT[(size_t)b * IDF * SLP + t];
    if (tid < IDF) cw_l[tid] = conv_w[tid];
    __syncthreads();
    if (tid < SL) {
        float a = 0.f;
#pragma unroll
        for (int i = 0; i < IDF; i++) a += cw_l[i] * st_l[i * SLP + tid];
        v_l[tid] = a;
    }
    __syncthreads();

    const int q = (blockIdx.x * 256 + tid) * 4;
    const float4* ip4 = (const float4*)(inp + (size_t)b * IDF * QL + q);

    float4 sc[SL];
#pragma unroll
    for (int s = 0; s < SL; s++) sc[s] = make_float4(0.f, 0.f, 0.f, 0.f);

#pragma unroll 8
    for (int i = 0; i < IDF; i++) {
        const float4 x = ip4[i * (QL / 4)];               // coalesced 16B/lane
        float r[SLP];
        const float4* r4 = (const float4*)&st_l[i * SLP]; // wave-uniform -> LDS broadcast
        ((float4*)r)[0] = r4[0];
        ((float4*)r)[1] = r4[1];
        ((float4*)r)[2] = r4[2];
        ((float4*)r)[3] = r4[3];
        ((float4*)r)[4] = r4[4];
#pragma unroll
        for (int s = 0; s < SL; s++) fma4(sc[s], x, r[s]);
    }

    float4 m = sc[0];
#pragma unroll
    for (int s = 1; s < SL; s++) {
        m.x = fmaxf(m.x, sc[s].x); m.y = fmaxf(m.y, sc[s].y);
        m.z = fmaxf(m.z, sc[s].z); m.w = fmaxf(m.w, sc[s].w);
    }
    float4 l = make_float4(0.f, 0.f, 0.f, 0.f);
    float4 o = make_float4(0.f, 0.f, 0.f, 0.f);
#pragma unroll
    for (int s = 0; s < SL; s++) {
        const float vs = v_l[s];
        float4 p;
        p.x = __expf(sc[s].x - m.x); p.y = __expf(sc[s].y - m.y);
        p.z = __expf(sc[s].z - m.z); p.w = __expf(sc[s].w - m.w);
        l.x += p.x; l.y += p.y; l.z += p.z; l.w += p.w;
        o.x += p.x * vs; o.y += p.y * vs; o.z += p.z * vs; o.w += p.w * vs;
    }
    const float cb = conv_b[0];
    float4 res;
    res.x = o.x / l.x + cb; res.y = o.y / l.y + cb;
    res.z = o.z / l.z + cb; res.w = o.w / l.w + cb;
    ((float4*)(wq + (size_t)b * QL))[blockIdx.x * 256 + tid] = res;
}

// ---------------- Kernel 3: out[b,a] = fc_b[a] + sum_q wq[b,q] * fc_w[a,q]
// grid = 200 blocks (8 b-groups x 25 a-groups), block 256 (4 waves).
// Block owns a 4b x 4a output tile over the FULL q-range: no atomics, no init.
__global__ __launch_bounds__(256, 2) void k3_fc(
        const float* __restrict__ wq,      // [B, QL]
        const float* __restrict__ fcw,     // [ADIM, QL]
        const float* __restrict__ fc_b,    // [ADIM]
        float* __restrict__ out)           // [B, ADIM]
{
    __shared__ float part[4 * 16];
    const int b4 = blockIdx.x / 25;
    const int ag = blockIdx.x - b4 * 25;
    const int b0 = b4 * 4, a0 = ag * 4;
    const int wave = threadIdx.x >> 6;
    const int lane = threadIdx.x & 63;
    const int q0 = wave * 4096;            // each wave: 4096 q

    float4 acc[4][4];
#pragma unroll
    for (int i = 0; i < 4; i++)
#pragma unroll
        for (int j = 0; j < 4; j++) acc[i][j] = make_float4(0.f, 0.f, 0.f, 0.f);

#pragma unroll 2
    for (int k = 0; k < 16; k++) {
        const int qi = q0 + (k * 64 + lane) * 4;
        float4 wv[4], fv[4];
#pragma unroll
        for (int i = 0; i < 4; i++) wv[i] = *(const float4*)(wq + (size_t)(b0 + i) * QL + qi);
#pragma unroll
        for (int j = 0; j < 4; j++) fv[j] = *(const float4*)(fcw + (size_t)(a0 + j) * QL + qi);
#pragma unroll
        for (int i = 0; i < 4; i++) {
#pragma unroll
            for (int j = 0; j < 4; j++) {
                acc[i][j].x += wv[i].x * fv[j].x;
                acc[i][j].y += wv[i].y * fv[j].y;
                acc[i][j].z += wv[i].z * fv[j].z;
                acc[i][j].w += wv[i].w * fv[j].w;
            }
        }
    }

#pragma unroll
    for (int i = 0; i < 4; i++) {
#pragma unroll
        for (int j = 0; j < 4; j++) {
            float r = acc[i][j].x + acc[i][j].y + acc[i][j].z + acc[i][j].w;
#pragma unroll
            for (int off = 32; off; off >>= 1) r += __shfl_xor(r, off, 64);
            if (lane == 0) part[wave * 16 + i * 4 + j] = r;
        }
    }
    __syncthreads();
    if (threadIdx.x < 16) {
        const int i = threadIdx.x >> 2;
        const int j = threadIdx.x & 3;
        const float s = part[threadIdx.x] + part[16 + threadIdx.x] +
                        part[32 + threadIdx.x] + part[48 + threadIdx.x];
        out[(b0 + i) * ADIM + a0 + j] = s + fc_b[a0 + j];
    }
}

extern "C" void kernel_launch(void* const* d_in, const int* in_sizes, int n_in,
                              void* d_out, int out_size, void* d_ws, size_t ws_size,
                              hipStream_t stream)
{
    const float* inputs     = (const float*)d_in[0];  // [32,64,128,128]
    const float* context    = (const float*)d_in[1];  // [32,768,18]
    const float* conv_ctx_w = (const float*)d_in[2];  // [64,768]
    const float* conv_w     = (const float*)d_in[3];  // [64]
    const float* conv_b     = (const float*)d_in[4];  // [1]
    const float* fc_w       = (const float*)d_in[5];  // [100,16384]
    const float* fc_b       = (const float*)d_in[6];  // [100]
    float* out = (float*)d_out;

    float* ws = (float*)d_ws;
    float* sT = ws;                                   // 32*64*20 = 40960 floats
    float* wq = ws + (size_t)BB * IDF * SLP;          // 524288 floats

    k1_source<<<dim3(BB, 4), dim3(256), 0, stream>>>(context, conv_ctx_w, sT);
    k2_attn<<<dim3(QL / 1024, BB), dim3(256), 0, stream>>>(inputs, sT, conv_w, conv_b, wq);
    k3_fc<<<dim3(200), dim3(256), 0, stream>>>(wq, fc_w, fc_b, out);
}

// Round 5
// 271.686 us; speedup vs baseline: 1.0059x; 1.0059x over previous
//
#include <hip/hip_runtime.h>

#define BB 32
#define IDF 64
#define QL 16384
#define CDF 768
#define SL 18
#define SLP 20             // padded row stride for ctx_l / sT
#define ADIM 100

__device__ __forceinline__ void fma4(float4& a, const float4 v, const float s) {
    a.x += v.x * s; a.y += v.y * s; a.z += v.z * s; a.w += v.w * s;
}

// ---------------- Kernel 1: sT[b,i,s] = sum_c wic[i,c] * ctx[b,c,s]
// grid = (32, 4), block = 256 (4 waves). Also initializes out[b,a] = fc_b[a]
// (blockIdx.y==0 blocks), so k3 can atomicAdd without a separate init launch.
__global__ __launch_bounds__(256, 2) void k1_source(
        const float* __restrict__ ctx,      // [B, CDF, SL]
        const float* __restrict__ wic,      // [IDF, CDF]
        const float* __restrict__ fc_b,     // [ADIM]
        float* __restrict__ sT,             // ws: [B, IDF, SLP]
        float* __restrict__ out)            // [B, ADIM]
{
    __shared__ __align__(16) float ctx_l[CDF * SLP];   // 61440 B
    const int b = blockIdx.x;
    const int g = blockIdx.y;

    // fused out-init (harness poisons out to 0xAA every launch)
    if (g == 0) {
        const int t = b * 256 + threadIdx.x;
        if (t < BB * ADIM) out[t] = fc_b[t % ADIM];
    }

    const float* ctxb = ctx + (size_t)b * CDF * SL;
    for (int t = threadIdx.x; t < CDF * SL; t += 256) {
        const int c = t / SL;
        const int s = t - c * SL;
        ctx_l[c * SLP + s] = ctxb[t];
    }
    __syncthreads();

    const int wave = threadIdx.x >> 6;
    const int lane = threadIdx.x & 63;
    const int i0 = g * 16 + wave * 4;

    float acc[4][SL];
#pragma unroll
    for (int ii = 0; ii < 4; ii++)
#pragma unroll
        for (int s = 0; s < SL; s++) acc[ii][s] = 0.f;

    for (int k = 0; k < CDF / 64; k++) {
        const int c = k * 64 + lane;
        float wv[4];
#pragma unroll
        for (int ii = 0; ii < 4; ii++) wv[ii] = wic[(i0 + ii) * CDF + c];  // coalesced
        float r[SLP];
        const float4* r4 = (const float4*)&ctx_l[c * SLP];
        ((float4*)r)[0] = r4[0];
        ((float4*)r)[1] = r4[1];
        ((float4*)r)[2] = r4[2];
        ((float4*)r)[3] = r4[3];
        ((float4*)r)[4] = r4[4];
#pragma unroll
        for (int ii = 0; ii < 4; ii++)
#pragma unroll
            for (int s = 0; s < SL; s++) acc[ii][s] += wv[ii] * r[s];
    }

#pragma unroll
    for (int ii = 0; ii < 4; ii++) {
#pragma unroll
        for (int s = 0; s < SL; s++) {
            float a = acc[ii][s];
#pragma unroll
            for (int off = 32; off; off >>= 1) a += __shfl_xor(a, off, 64);
            if (lane == 0) sT[((size_t)b * IDF + i0 + ii) * SLP + s] = a;
        }
    }
}

// ---------------- Kernel 2: scores -> softmax -> dot with v.  HBM-bound main pass.
// grid = (16, 32), block = 256, 4 q per thread (float4). Explicit register
// double-buffer: next 8 input loads issue before current 8 FMA batches.
// Grid-limited to 8 waves/CU, so ~170 VGPR is free (2 waves/SIMD).
__global__ __launch_bounds__(256, 2) void k2_attn(
        const float* __restrict__ inp,     // [B, IDF, QL]
        const float* __restrict__ sT,      // [B, IDF, SLP]
        const float* __restrict__ conv_w,  // [IDF]
        const float* __restrict__ conv_b,  // [1]
        float* __restrict__ wq)            // ws: [B, QL]
{
    __shared__ __align__(16) float st_l[IDF * SLP];   // 5120 B
    __shared__ float cw_l[IDF];
    __shared__ float v_l[SL];
    const int b = blockIdx.y;
    const int tid = threadIdx.x;

    for (int t = tid; t < IDF * SLP; t += 256) st_l[t] = sT[(size_t)b * IDF * SLP + t];
    if (tid < IDF) cw_l[tid] = conv_w[tid];
    __syncthreads();
    if (tid < SL) {
        float a = 0.f;
#pragma unroll
        for (int i = 0; i < IDF; i++) a += cw_l[i] * st_l[i * SLP + tid];
        v_l[tid] = a;
    }
    __syncthreads();

    const int q = (blockIdx.x * 256 + tid) * 4;
    const float4* ip4 = (const float4*)(inp + (size_t)b * IDF * QL + q);

    float4 sc[SL];
#pragma unroll
    for (int s = 0; s < SL; s++) sc[s] = make_float4(0.f, 0.f, 0.f, 0.f);

    float4 xa[8];
#pragma unroll
    for (int j = 0; j < 8; j++) xa[j] = ip4[(size_t)j * (QL / 4)];

#pragma unroll
    for (int c = 0; c < 8; c++) {
        float4 xb[8];
        if (c < 7) {
#pragma unroll
            for (int j = 0; j < 8; j++) xb[j] = ip4[(size_t)((c + 1) * 8 + j) * (QL / 4)];
        }
#pragma unroll
        for (int j = 0; j < 8; j++) {
            const int i = c * 8 + j;
            float r[SLP];
            const float4* r4 = (const float4*)&st_l[i * SLP];  // wave-uniform -> broadcast
            ((float4*)r)[0] = r4[0];
            ((float4*)r)[1] = r4[1];
            ((float4*)r)[2] = r4[2];
            ((float4*)r)[3] = r4[3];
            ((float4*)r)[4] = r4[4];
#pragma unroll
            for (int s = 0; s < SL; s++) fma4(sc[s], xa[j], r[s]);
        }
        if (c < 7) {
#pragma unroll
            for (int j = 0; j < 8; j++) xa[j] = xb[j];
        }
    }

    float4 m = sc[0];
#pragma unroll
    for (int s = 1; s < SL; s++) {
        m.x = fmaxf(m.x, sc[s].x); m.y = fmaxf(m.y, sc[s].y);
        m.z = fmaxf(m.z, sc[s].z); m.w = fmaxf(m.w, sc[s].w);
    }
    float4 l = make_float4(0.f, 0.f, 0.f, 0.f);
    float4 o = make_float4(0.f, 0.f, 0.f, 0.f);
#pragma unroll
    for (int s = 0; s < SL; s++) {
        const float vs = v_l[s];
        float4 p;
        p.x = __expf(sc[s].x - m.x); p.y = __expf(sc[s].y - m.y);
        p.z = __expf(sc[s].z - m.z); p.w = __expf(sc[s].w - m.w);
        l.x += p.x; l.y += p.y; l.z += p.z; l.w += p.w;
        o.x += p.x * vs; o.y += p.y * vs; o.z += p.z * vs; o.w += p.w * vs;
    }
    const float cb = conv_b[0];
    float4 res;
    res.x = o.x / l.x + cb; res.y = o.y / l.y + cb;
    res.z = o.z / l.z + cb; res.w = o.w / l.w + cb;
    ((float4*)(wq + (size_t)b * QL))[blockIdx.x * 256 + tid] = res;
}

// ---------------- Kernel 3: out[b,a] += sum_q wq[b,q] * fc_w[a,q]
// 400 blocks / 1600 waves; wave = (4b x 4a x 2048q) register tile; coalesced
// float4 reads; butterfly reduce; 8 atomics per output address (onto fc_b init).
__global__ __launch_bounds__(256, 2) void k3_fc(
        const float* __restrict__ wq,      // [B, QL]
        const float* __restrict__ fcw,     // [ADIM, QL]
        float* __restrict__ out)           // [B, ADIM]
{
    const int w = blockIdx.x * 4 + (threadIdx.x >> 6);   // 1600 waves
    const int lane = threadIdx.x & 63;
    const int b4 = w / 200;
    const int rem = w - b4 * 200;
    const int ag = rem >> 3;          // 0..24
    const int qc = rem & 7;           // 0..7
    const int b0 = b4 * 4, a0 = ag * 4, q0 = qc * 2048;

    float4 acc[4][4];
#pragma unroll
    for (int i = 0; i < 4; i++)
#pragma unroll
        for (int j = 0; j < 4; j++) acc[i][j] = make_float4(0.f, 0.f, 0.f, 0.f);

#pragma unroll 4
    for (int k = 0; k < 8; k++) {
        const int qi = q0 + (k * 64 + lane) * 4;
        float4 wv[4], fv[4];
#pragma unroll
        for (int i = 0; i < 4; i++) wv[i] = *(const float4*)(wq + (size_t)(b0 + i) * QL + qi);
#pragma unroll
        for (int j = 0; j < 4; j++) fv[j] = *(const float4*)(fcw + (size_t)(a0 + j) * QL + qi);
#pragma unroll
        for (int i = 0; i < 4; i++) {
#pragma unroll
            for (int j = 0; j < 4; j++) {
                acc[i][j].x += wv[i].x * fv[j].x;
                acc[i][j].y += wv[i].y * fv[j].y;
                acc[i][j].z += wv[i].z * fv[j].z;
                acc[i][j].w += wv[i].w * fv[j].w;
            }
        }
    }

#pragma unroll
    for (int i = 0; i < 4; i++) {
#pragma unroll
        for (int j = 0; j < 4; j++) {
            float r = acc[i][j].x + acc[i][j].y + acc[i][j].z + acc[i][j].w;
#pragma unroll
            for (int off = 32; off; off >>= 1) r += __shfl_xor(r, off, 64);
            if (lane == 0) atomicAdd(&out[(b0 + i) * ADIM + a0 + j], r);
        }
    }
}

extern "C" void kernel_launch(void* const* d_in, const int* in_sizes, int n_in,
                              void* d_out, int out_size, void* d_ws, size_t ws_size,
                              hipStream_t stream)
{
    const float* inputs     = (const float*)d_in[0];  // [32,64,128,128]
    const float* context    = (const float*)d_in[1];  // [32,768,18]
    const float* conv_ctx_w = (const float*)d_in[2];  // [64,768]
    const float* conv_w     = (const float*)d_in[3];  // [64]
    const float* conv_b     = (const float*)d_in[4];  // [1]
    const float* fc_w       = (const float*)d_in[5];  // [100,16384]
    const float* fc_b       = (const float*)d_in[6];  // [100]
    float* out = (float*)d_out;

    float* ws = (float*)d_ws;
    float* sT = ws;                                   // 32*64*20 = 40960 floats
    float* wq = ws + (size_t)BB * IDF * SLP;          // 524288 floats

    k1_source<<<dim3(BB, 4), dim3(256), 0, stream>>>(context, conv_ctx_w, fc_b, sT, out);
    k2_attn<<<dim3(QL / 1024, BB), dim3(256), 0, stream>>>(inputs, sT, conv_w, conv_b, wq);
    k3_fc<<<dim3(400), dim3(256), 0, stream>>>(wq, fc_w, out);
}

// Round 7
// 271.672 us; speedup vs baseline: 1.0059x; 1.0001x over previous
//
#include <hip/hip_runtime.h>

#define BB 32
#define IDF 64
#define QL 16384
#define CDF 768
#define SL 18
#define SLP 20             // padded row stride for sT
#define ADIM 100

__device__ __forceinline__ void fma4(float4& a, const float4 v, const float s) {
    a.x += v.x * s; a.y += v.y * s; a.z += v.z * s; a.w += v.w * s;
}

// ---------------- Kernel A: sT[b,i,s] = sum_c wic[i,c] * ctx[b,c,s]; out init.
// grid = (32, 4), block = 256 (4 waves). Proven non-spilling (VGPR 128).
__global__ __launch_bounds__(256, 2) void kA_source(
        const float* __restrict__ ctx,      // [B, CDF, SL]
        const float* __restrict__ wic,      // [IDF, CDF]
        const float* __restrict__ fc_b,     // [ADIM]
        float* __restrict__ sT,             // ws: [B, IDF, SLP]
        float* __restrict__ out)            // [B, ADIM]
{
    __shared__ __align__(16) float ctx_l[CDF * SLP];   // 61440 B
    const int b = blockIdx.x;
    const int g = blockIdx.y;

    // fused out-init (harness poisons out every launch); B's atomics add onto this
    if (g == 0) {
        const int t = b * 256 + threadIdx.x;
        if (t < BB * ADIM) out[t] = fc_b[t % ADIM];
    }

    const float* ctxb = ctx + (size_t)b * CDF * SL;
    for (int t = threadIdx.x; t < CDF * SL; t += 256) {
        const int c = t / SL;
        const int s = t - c * SL;
        ctx_l[c * SLP + s] = ctxb[t];
    }
    __syncthreads();

    const int wave = threadIdx.x >> 6;
    const int lane = threadIdx.x & 63;
    const int i0 = g * 16 + wave * 4;

    float acc[4][SL];
#pragma unroll
    for (int ii = 0; ii < 4; ii++)
#pragma unroll
        for (int s = 0; s < SL; s++) acc[ii][s] = 0.f;

    for (int k = 0; k < CDF / 64; k++) {
        const int c = k * 64 + lane;
        float wv[4];
#pragma unroll
        for (int ii = 0; ii < 4; ii++) wv[ii] = wic[(i0 + ii) * CDF + c];  // coalesced
        float r[SLP];
        const float4* r4 = (const float4*)&ctx_l[c * SLP];
        ((float4*)r)[0] = r4[0];
        ((float4*)r)[1] = r4[1];
        ((float4*)r)[2] = r4[2];
        ((float4*)r)[3] = r4[3];
        ((float4*)r)[4] = r4[4];
#pragma unroll
        for (int ii = 0; ii < 4; ii++)
#pragma unroll
            for (int s = 0; s < SL; s++) acc[ii][s] += wv[ii] * r[s];
    }

#pragma unroll
    for (int ii = 0; ii < 4; ii++) {
#pragma unroll
        for (int s = 0; s < SL; s++) {
            float a = acc[ii][s];
#pragma unroll
            for (int off = 32; off; off >>= 1) a += __shfl_xor(a, off, 64);
            if (lane == 0) sT[((size_t)b * IDF + i0 + ii) * SLP + s] = a;
        }
    }
}

// ---------------- Kernel B: attn softmax + fc contraction, fused per q-tile.
// grid = (16, 32): blockIdx.x = q-tile (1024 q), blockIdx.y = b. block = 256.
// Phase 2: scores->softmax->wq (kept in LDS, never globalized).
// Phase 3: out[b,a] += sum_{q in tile} wq_l[q] * fcw[a,q]  (16-way atomics).
__global__ __launch_bounds__(256, 2) void kB_attn_fc(
        const float* __restrict__ inp,     // [B, IDF, QL]
        const float* __restrict__ sT,      // [B, IDF, SLP]
        const float* __restrict__ conv_w,  // [IDF]
        const float* __restrict__ conv_b,  // [1]
        const float* __restrict__ fcw,     // [ADIM, QL]
        float* __restrict__ out)           // [B, ADIM]
{
    __shared__ __align__(16) float st_l[IDF * SLP];   // 5120 B
    __shared__ __align__(16) float wq_l[1024];        // 4096 B
    __shared__ float cw_l[IDF];
    __shared__ float v_l[SL];
    const int b  = blockIdx.y;
    const int qt = blockIdx.x;
    const int tid = threadIdx.x;
    const int wave = tid >> 6;
    const int lane = tid & 63;

    for (int t = tid; t < IDF * SLP; t += 256) st_l[t] = sT[(size_t)b * IDF * SLP + t];
    if (tid < IDF) cw_l[tid] = conv_w[tid];
    __syncthreads();
    if (tid < SL) {
        float a = 0.f;
#pragma unroll
        for (int i = 0; i < IDF; i++) a += cw_l[i] * st_l[i * SLP + tid];
        v_l[tid] = a;
    }
    __syncthreads();

    // ---- Phase 2: 4 q per thread (float4 stream over inputs)
    const int q = (qt * 256 + tid) * 4;
    const float4* ip4 = (const float4*)(inp + (size_t)b * IDF * QL + q);

    float4 sc[SL];
#pragma unroll
    for (int s = 0; s < SL; s++) sc[s] = make_float4(0.f, 0.f, 0.f, 0.f);

#pragma unroll 8
    for (int i = 0; i < IDF; i++) {
        const float4 x = ip4[(size_t)i * (QL / 4)];       // coalesced 16B/lane
        float r[SLP];
        const float4* r4 = (const float4*)&st_l[i * SLP]; // wave-uniform broadcast
        ((float4*)r)[0] = r4[0];
        ((float4*)r)[1] = r4[1];
        ((float4*)r)[2] = r4[2];
        ((float4*)r)[3] = r4[3];
        ((float4*)r)[4] = r4[4];
#pragma unroll
        for (int s = 0; s < SL; s++) fma4(sc[s], x, r[s]);
    }

    float4 m = sc[0];
#pragma unroll
    for (int s = 1; s < SL; s++) {
        m.x = fmaxf(m.x, sc[s].x); m.y = fmaxf(m.y, sc[s].y);
        m.z = fmaxf(m.z, sc[s].z); m.w = fmaxf(m.w, sc[s].w);
    }
    float4 l = make_float4(0.f, 0.f, 0.f, 0.f);
    float4 o = make_float4(0.f, 0.f, 0.f, 0.f);
#pragma unroll
    for (int s = 0; s < SL; s++) {
        const float vs = v_l[s];
        float4 p;
        p.x = __expf(sc[s].x - m.x); p.y = __expf(sc[s].y - m.y);
        p.z = __expf(sc[s].z - m.z); p.w = __expf(sc[s].w - m.w);
        l.x += p.x; l.y += p.y; l.z += p.z; l.w += p.w;
        o.x += p.x * vs; o.y += p.y * vs; o.z += p.z * vs; o.w += p.w * vs;
    }
    const float cb = conv_b[0];
    float4 res;
    res.x = o.x / l.x + cb; res.y = o.y / l.y + cb;
    res.z = o.z / l.z + cb; res.w = o.w / l.w + cb;
    ((float4*)wq_l)[tid] = res;
    __syncthreads();

    // ---- Phase 3: wave w handles a in [25w, 25w+25); 4 passes of 256 q each.
    const float* fcw_t = fcw + (size_t)qt * 1024;
#pragma unroll 1
    for (int aa = 0; aa < 25; aa++) {
        const int a = wave * 25 + aa;
        const float* fr = fcw_t + (size_t)a * QL;
        float acc = 0.f;
#pragma unroll
        for (int pass = 0; pass < 4; pass++) {
            const int qi = pass * 256 + lane * 4;
            const float4 f = *(const float4*)(fr + qi);      // coalesced, L2/L3-hot
            const float4 w = *(const float4*)(wq_l + qi);    // LDS
            acc += f.x * w.x + f.y * w.y + f.z * w.z + f.w * w.w;
        }
#pragma unroll
        for (int off = 32; off; off >>= 1) acc += __shfl_xor(acc, off, 64);
        if (lane == 0) atomicAdd(&out[b * ADIM + a], acc);
    }
}

extern "C" void kernel_launch(void* const* d_in, const int* in_sizes, int n_in,
                              void* d_out, int out_size, void* d_ws, size_t ws_size,
                              hipStream_t stream)
{
    const float* inputs     = (const float*)d_in[0];  // [32,64,128,128]
    const float* context    = (const float*)d_in[1];  // [32,768,18]
    const float* conv_ctx_w = (const float*)d_in[2];  // [64,768]
    const float* conv_w     = (const float*)d_in[3];  // [64]
    const float* conv_b     = (const float*)d_in[4];  // [1]
    const float* fc_w       = (const float*)d_in[5];  // [100,16384]
    const float* fc_b       = (const float*)d_in[6];  // [100]
    float* out = (float*)d_out;

    float* ws = (float*)d_ws;
    float* sT = ws;                                   // 32*64*20 = 40960 floats

    kA_source<<<dim3(BB, 4), dim3(256), 0, stream>>>(context, conv_ctx_w, fc_b, sT, out);
    kB_attn_fc<<<dim3(16, BB), dim3(256), 0, stream>>>(inputs, sT, conv_w, conv_b, fc_w, out);
}

// Round 8
// 239.722 us; speedup vs baseline: 1.1400x; 1.1333x over previous
//
#include <hip/hip_runtime.h>

#define BB 32
#define IDF 64
#define QL 16384
#define CDF 768
#define SL 18
#define SLP 20             // padded row stride for sT
#define ADIM 100

// ---------------- Kernel A: sT[b,i,s] = sum_c wic[i,c] * ctx[b,c,s]; out init.
// grid = 512 blocks x 256: one wave per (b,i) row. ctx read direct (L2/L3-hot,
// 113 MB aggregate); no LDS staging, no bank conflicts, full-machine grid.
__global__ __launch_bounds__(256, 2) void kA_source(
        const float* __restrict__ ctx,      // [B, CDF, SL]
        const float* __restrict__ wic,      // [IDF, CDF]
        const float* __restrict__ fc_b,     // [ADIM]
        float* __restrict__ sT,             // ws: [B, IDF, SLP]
        float* __restrict__ out)            // [B, ADIM]
{
    const int blk  = blockIdx.x;
    const int tid  = threadIdx.x;
    const int wave = tid >> 6;
    const int lane = tid & 63;

    // fused out-init (harness poisons out every launch); kB atomics add onto it
    if (blk < 13) {
        const int t = blk * 256 + tid;
        if (t < BB * ADIM) out[t] = fc_b[t % ADIM];
    }

    const int b = blk >> 4;
    const int i = (blk & 15) * 4 + wave;
    const float* ctxb = ctx + (size_t)b * CDF * SL;
    const float* wrow = wic + (size_t)i * CDF;

    float acc[SL];
#pragma unroll
    for (int s = 0; s < SL; s++) acc[s] = 0.f;

#pragma unroll 2
    for (int k = 0; k < CDF / 64; k++) {
        const int c = k * 64 + lane;
        const float wv = wrow[c];                    // coalesced 256 B/wave
        const float* cr = ctxb + (size_t)c * SL;     // 72 B/lane, wave covers 4.6 KB contig
        float r[SL];
#pragma unroll
        for (int s = 0; s < SL; s++) r[s] = cr[s];
#pragma unroll
        for (int s = 0; s < SL; s++) acc[s] += wv * r[s];
    }
#pragma unroll
    for (int s = 0; s < SL; s++) {
        float a = acc[s];
#pragma unroll
        for (int off = 32; off; off >>= 1) a += __shfl_xor(a, off, 64);
        if (lane == 0) sT[((size_t)b * IDF + i) * SLP + s] = a;
    }
}

// ---------------- Kernel B: attn softmax + fc contraction, fused per q-tile.
// grid = (32, 32): blockIdx.x = qt (512 q), blockIdx.y = b. 1024 blocks =
// 4 blocks/CU = 16 waves/CU. 2 q per thread (float2): sc[18] float2 = 36 VGPR,
// rolling 4-deep input prefetch — low register footprint, latency hidden by TLP.
__global__ __launch_bounds__(256, 2) void kB_attn_fc(
        const float* __restrict__ inp,     // [B, IDF, QL]
        const float* __restrict__ sT,      // [B, IDF, SLP]
        const float* __restrict__ conv_w,  // [IDF]
        const float* __restrict__ conv_b,  // [1]
        const float* __restrict__ fcw,     // [ADIM, QL]
        float* __restrict__ out)           // [B, ADIM]
{
    __shared__ __align__(16) float st_l[IDF * SLP];   // 5120 B
    __shared__ __align__(16) float wq_l[512];         // 2048 B
    __shared__ float cw_l[IDF];
    __shared__ float v_l[SL];
    const int b   = blockIdx.y;
    const int qt  = blockIdx.x;
    const int tid = threadIdx.x;
    const int wave = tid >> 6;
    const int lane = tid & 63;

    for (int t = tid; t < IDF * SLP; t += 256) st_l[t] = sT[(size_t)b * IDF * SLP + t];
    if (tid < IDF) cw_l[tid] = conv_w[tid];
    __syncthreads();
    if (tid < SL) {
        float a = 0.f;
#pragma unroll
        for (int i = 0; i < IDF; i++) a += cw_l[i] * st_l[i * SLP + tid];
        v_l[tid] = a;
    }
    __syncthreads();

    // ---- Phase 2: 2 q per thread (float2), rolling 4-deep prefetch.
    const float2* ip2 = (const float2*)(inp + (size_t)b * IDF * QL + (size_t)qt * 512);

    float2 sc[SL];
#pragma unroll
    for (int s = 0; s < SL; s++) sc[s] = make_float2(0.f, 0.f);

    float2 xb[4];
#pragma unroll
    for (int j = 0; j < 4; j++) xb[j] = ip2[(size_t)j * (QL / 2) + tid];

#pragma unroll 4
    for (int i = 0; i < IDF; i++) {
        const float2 x = xb[i & 3];
        if (i + 4 < IDF) xb[i & 3] = ip2[(size_t)(i + 4) * (QL / 2) + tid];
        float r[SL];
        const float4* r4 = (const float4*)&st_l[i * SLP];  // wave-uniform -> broadcast
        ((float4*)r)[0] = r4[0];
        ((float4*)r)[1] = r4[1];
        ((float4*)r)[2] = r4[2];
        ((float4*)r)[3] = r4[3];
        ((float2*)(r + 16))[0] = *(const float2*)&st_l[i * SLP + 16];
#pragma unroll
        for (int s = 0; s < SL; s++) {
            sc[s].x += x.x * r[s];
            sc[s].y += x.y * r[s];
        }
    }

    float2 m = sc[0];
#pragma unroll
    for (int s = 1; s < SL; s++) {
        m.x = fmaxf(m.x, sc[s].x);
        m.y = fmaxf(m.y, sc[s].y);
    }
    float2 l = make_float2(0.f, 0.f);
    float2 o = make_float2(0.f, 0.f);
#pragma unroll
    for (int s = 0; s < SL; s++) {
        const float vs = v_l[s];
        float2 p;
        p.x = __expf(sc[s].x - m.x);
        p.y = __expf(sc[s].y - m.y);
        l.x += p.x; l.y += p.y;
        o.x += p.x * vs; o.y += p.y * vs;
    }
    const float cb = conv_b[0];
    float2 res;
    res.x = o.x / l.x + cb;
    res.y = o.y / l.y + cb;
    ((float2*)wq_l)[tid] = res;
    __syncthreads();

    // ---- Phase 3: out[b,a] += sum_{q in tile} wq_l * fcw[a, tile].
    // Wave w: a in [25w, 25w+25). wq read ONCE per wave into regs (8 floats/lane).
    float wv[8];
    ((float4*)wv)[0] = *(const float4*)&wq_l[lane * 8];
    ((float4*)wv)[1] = *(const float4*)&wq_l[lane * 8 + 4];

    const float* fcw_t = fcw + (size_t)qt * 512;
#pragma unroll 1
    for (int aa = 0; aa < 25; aa++) {
        const int a = wave * 25 + aa;
        const float* fr = fcw_t + (size_t)a * QL + lane * 8;
        float4 f0 = *(const float4*)fr;
        float4 f1 = *(const float4*)(fr + 4);
        float acc = f0.x * wv[0] + f0.y * wv[1] + f0.z * wv[2] + f0.w * wv[3]
                  + f1.x * wv[4] + f1.y * wv[5] + f1.z * wv[6] + f1.w * wv[7];
#pragma unroll
        for (int off = 32; off; off >>= 1) acc += __shfl_xor(acc, off, 64);
        if (lane == 0) atomicAdd(&out[b * ADIM + a], acc);
    }
}

extern "C" void kernel_launch(void* const* d_in, const int* in_sizes, int n_in,
                              void* d_out, int out_size, void* d_ws, size_t ws_size,
                              hipStream_t stream)
{
    const float* inputs     = (const float*)d_in[0];  // [32,64,128,128]
    const float* context    = (const float*)d_in[1];  // [32,768,18]
    const float* conv_ctx_w = (const float*)d_in[2];  // [64,768]
    const float* conv_w     = (const float*)d_in[3];  // [64]
    const float* conv_b     = (const float*)d_in[4];  // [1]
    const float* fc_w       = (const float*)d_in[5];  // [100,16384]
    const float* fc_b       = (const float*)d_in[6];  // [100]
    float* out = (float*)d_out;

    float* ws = (float*)d_ws;
    float* sT = ws;                                   // 32*64*20 = 40960 floats

    kA_source<<<dim3(512), dim3(256), 0, stream>>>(context, conv_ctx_w, fc_b, sT, out);
    kB_attn_fc<<<dim3(32, BB), dim3(256), 0, stream>>>(inputs, sT, conv_w, conv_b, fc_w, out);
}